// Round 6
// baseline (259.294 us; speedup 1.0000x reference)
//
#include <hip/hip_runtime.h>
#include <hip/hip_bf16.h>

// (B, LIN, E, D, N) = (32, 2048, 512, 512, 2)
#define L_SZ 2048
#define E_SZ 512
#define D_SZ 512
#define ND   1024
// ws layout: dec_proj (32*512 f32) | Bt (512*512 bf16, [n][k]) | scores (32*2048 f32)
#define WS_DEC_OFF 0
#define WS_BT_OFF  (32*512*4)
#define WS_SC_OFF  (32*512*4 + 512*512*2)

typedef unsigned short ushort_t;
typedef unsigned int   uint_t;
typedef __attribute__((ext_vector_type(8))) short short8;   // 8 bf16 (MFMA A/B frag)
typedef __attribute__((ext_vector_type(4))) float floatx4;  // MFMA C/D frag
typedef __attribute__((ext_vector_type(4))) float fvec4;    // clang-native float4

__device__ __forceinline__ ushort_t f2bf(float f) {
  uint_t u = __builtin_bit_cast(uint_t, f);
  u += 0x7fffu + ((u >> 16) & 1u);
  return (ushort_t)(u >> 16);
}

__device__ __forceinline__ float fast_tanh(float x) {
  float e = __expf(2.0f * x);
  return 1.0f - 2.0f * __builtin_amdgcn_rcpf(e + 1.0f);
}

// async 16B global->LDS DMA; lptr must be wave-uniform, HW deposits lane i at lptr + 16*i
__device__ __forceinline__ void dma16(const ushort_t* g, ushort_t* l) {
  __builtin_amdgcn_global_load_lds(
      (const __attribute__((address_space(1))) uint_t*)(const void*)g,
      (__attribute__((address_space(3))) uint_t*)(void*)l,
      16, 0, 0);
}

// ---------------------------------------------------------------------------
// Prep, 512 blocks:
//  blocks 0..255  : dec_proj[b][d] (b=blk>>3, d-tile=blk&7), k split 4-way + LDS reduce
//  blocks 256..511: Bt[n][k] = bf16(W1[1024+k][n]) via 32x32 LDS transpose tiles
// ---------------------------------------------------------------------------
__global__ __launch_bounds__(256) void prep_k(const float* __restrict__ dh,
                                              const float* __restrict__ W1,
                                              const float* __restrict__ b1,
                                              float* __restrict__ dec,
                                              ushort_t* __restrict__ Bt) {
  int blk = blockIdx.x, t = threadIdx.x;
  if (blk < 256) {
    int b = blk >> 3, d = (blk & 7) * 64 + (t & 63);
    int q = t >> 6;
    __shared__ float red[4][64];
    const float* dfb = dh + b * ND;
    float s = 0.f;
    #pragma unroll 8
    for (int k = q * 256; k < q * 256 + 256; k++)
      s = fmaf(dfb[k], W1[k * D_SZ + d], s);
    red[q][t & 63] = s;
    __syncthreads();
    if (q == 0)
      dec[b * D_SZ + d] = red[0][t] + red[1][t] + red[2][t] + red[3][t] + b1[d];
  } else {
    int tid = blk - 256;
    int tk = (tid >> 4) * 32, tn = (tid & 15) * 32;
    __shared__ float tile[32][33];
    int cc = t & 31, r8 = t >> 5;
    #pragma unroll
    for (int p = 0; p < 4; p++) {
      int r = r8 + p * 8;
      tile[r][cc] = W1[(ND + tk + r) * D_SZ + tn + cc];
    }
    __syncthreads();
    #pragma unroll
    for (int p = 0; p < 4; p++) {
      int nn = r8 + p * 8;
      Bt[(tn + nn) * E_SZ + tk + cc] = f2bf(tile[cc][nn]);
    }
  }
}

// ---------------------------------------------------------------------------
// Main (round 6): r0 geometry + T4 counted-vmcnt schedule.
// WG = 512 threads (8 waves) = 64 rows x ALL 512 cols. K = 512, BK=64, 8 windows.
// Wave w owns cols [w*64, w*64+64): 4mt x 4nt 16x16x32 tiles, acc[4][4].
//
// KEY PROPERTY: wave w DEPOSITS exactly the Bs rows it CONSUMES
// (rows [w*64, w*64+64), via 8 dma16 with pre-XOR-swizzled source). So B needs
// NO barrier: each wave orders its own DMAs with a counted s_waitcnt vmcnt(10)
// (drains the 1-window-old B(kw)+A(kw+1); leaves this window's 10 issues in
// flight). vmcnt NEVER drains to 0 in the loop (T4/m218: drain-0 was the
// +40-70% stall). Only the 8KB A tile is cross-wave: its barrier drains
// lgkmcnt ONLY (~50cy) — no global round-trip at any barrier.
// A is loaded 2 windows ahead (HBM ~900cy covered by ~2 window bodies).
// LDS = 2x64 (Bs) + 2x8 (As) KB -> 1 block/CU; pipeline supplies the overlap.
// ---------------------------------------------------------------------------
__global__ __launch_bounds__(512, 2) void main_k(const float* __restrict__ enc,
                                                 const ushort_t* __restrict__ Bt,
                                                 const float* __restrict__ dec,
                                                 const float* __restrict__ w2,
                                                 float* __restrict__ scores) {
  const int b  = blockIdx.y;
  const int l0 = blockIdx.x * 64;
  const int t  = threadIdx.x;            // 0..511
  const int wave = t >> 6, lane = t & 63;
  const int col = lane & 15, quad = lane >> 4;

  __shared__ __align__(16) ushort_t Bs[2][512 * 64];  // 2 x 64 KB, [n][k] 128B rows, XOR-swz
  __shared__ __align__(16) ushort_t As[2][64 * 64];   // 2 x 8 KB,  [m][k] 128B rows, XOR-swz
  __shared__ float s_sc[64];

  if (t < 64) s_sc[t] = 0.f;

  floatx4 acc[4][4];
  #pragma unroll
  for (int mt = 0; mt < 4; mt++)
    #pragma unroll
    for (int nt = 0; nt < 4; nt++)
      acc[mt][nt] = (floatx4){0.f, 0.f, 0.f, 0.f};

  const float* arow = enc + (size_t)(b * L_SZ + l0) * E_SZ;

  // A: thread t owns chunk t: row am, chunk ac (8 floats -> 8 bf16 = 16B)
  const int am = t >> 3, ac = t & 7;
  const float* aptr = arow + am * E_SZ + ac * 8;
  const int awoff = am * 64 + ((ac ^ (am & 7)) << 3);

  // B DMA source mapping (r0-verified): slot s = wave*512 + j*64 + lane;
  // n = s>>3 in [wave*64, wave*64+64); c = (s&7)^(n&7)  (pre-swizzled source
  // so the linear deposit lands in the XOR-swizzled layout).
  const int bn0 = wave * 64 + (lane >> 3);
  const int bc0 = (lane & 7) ^ ((lane >> 3) & 7);
  const ushort_t* bptr0 = Bt + bn0 * E_SZ + bc0 * 8;

  // ---- prologue: A(0) loads, B(0) DMAs, A(1) loads; cvt A(0)->As[0] ----
  fvec4 ra0 = *(const fvec4*)aptr;                     // A(0): 2 vm ops
  fvec4 ra1 = *(const fvec4*)(aptr + 4);
  #pragma unroll
  for (int j = 0; j < 8; j++)                          // B(0): 8 vm ops
    dma16(bptr0 + j * 8 * E_SZ, &Bs[0][wave * 4096 + j * 512]);
  fvec4 rn0 = *(const fvec4*)(aptr + 64);              // A(1): 2 vm ops
  fvec4 rn1 = *(const fvec4*)(aptr + 68);
  asm volatile("s_waitcnt vmcnt(10)" ::: "memory");    // drain A(0); keep B(0),A(1)
  {
    union { short8 v; __hip_bfloat162 h[4]; } pk;
    pk.h[0] = __float22bfloat162_rn(make_float2(ra0.x, ra0.y));
    pk.h[1] = __float22bfloat162_rn(make_float2(ra0.z, ra0.w));
    pk.h[2] = __float22bfloat162_rn(make_float2(ra1.x, ra1.y));
    pk.h[3] = __float22bfloat162_rn(make_float2(ra1.z, ra1.w));
    *(short8*)&As[0][awoff] = pk.v;
  }
  // regA := A(1)
  ra0 = rn0; ra1 = rn1;
  asm volatile("s_waitcnt lgkmcnt(0)" ::: "memory");
  __builtin_amdgcn_s_barrier();
  __builtin_amdgcn_sched_barrier(0);

  #pragma unroll 1
  for (int kw = 0; kw < 8; kw++) {
    const ushort_t* Acur = &As[kw & 1][0];
    const ushort_t* Bcur = &Bs[kw & 1][0];

    // ---- 1. issue next loads: A(kw+2) -> regs (2), B(kw+1) -> Bs[nxt] (8) ----
    if (kw < 6) {
      const float* ap = aptr + (kw + 2) * 64;
      rn0 = *(const fvec4*)ap;
      rn1 = *(const fvec4*)(ap + 4);
    }
    if (kw < 7) {
      const ushort_t* bp = bptr0 + (kw + 1) * 64;
      ushort_t* bld = &Bs[(kw + 1) & 1][wave * 4096];
      #pragma unroll
      for (int j = 0; j < 8; j++)
        dma16(bp + j * 8 * E_SZ, bld + j * 512);
    }

    // ---- 2. counted wait: drain B(kw)+A(kw+1) (1 window old); keep new issues ----
    if (kw < 6)      asm volatile("s_waitcnt vmcnt(10)" ::: "memory");
    else if (kw == 6) asm volatile("s_waitcnt vmcnt(8)"  ::: "memory");
    else              asm volatile("s_waitcnt vmcnt(0)"  ::: "memory");

    // ---- 3. cvt A(kw+1) regs -> As[nxt] ----
    if (kw < 7) {
      union { short8 v; __hip_bfloat162 h[4]; } pk;
      pk.h[0] = __float22bfloat162_rn(make_float2(ra0.x, ra0.y));
      pk.h[1] = __float22bfloat162_rn(make_float2(ra0.z, ra0.w));
      pk.h[2] = __float22bfloat162_rn(make_float2(ra1.x, ra1.y));
      pk.h[3] = __float22bfloat162_rn(make_float2(ra1.z, ra1.w));
      *(short8*)&As[(kw + 1) & 1][awoff] = pk.v;
      ra0 = rn0; ra1 = rn1;                            // regA := regN
    }

    // ---- 4. MFMA on cur (Bs region is this wave's own deposit; As via barrier) ----
    #pragma unroll
    for (int ks = 0; ks < 2; ks++) {
      short8 af[4], bfr[4];
      #pragma unroll
      for (int mt = 0; mt < 4; mt++) {
        int m = mt * 16 + col;
        af[mt] = *(const short8*)&Acur[m * 64 + ((((ks << 2) + quad) ^ (m & 7)) << 3)];
      }
      #pragma unroll
      for (int nt = 0; nt < 4; nt++) {
        int n = wave * 64 + nt * 16 + col;
        bfr[nt] = *(const short8*)&Bcur[n * 64 + ((((ks << 2) + quad) ^ (n & 7)) << 3)];
      }
      #pragma unroll
      for (int mt = 0; mt < 4; mt++)
        #pragma unroll
        for (int nt = 0; nt < 4; nt++)
          acc[mt][nt] = __builtin_amdgcn_mfma_f32_16x16x32_bf16(af[mt], bfr[nt], acc[mt][nt], 0, 0, 0);
    }

    // ---- 5. window boundary: lgkm-only drain (A ds_writes visible), no vm drain ----
    asm volatile("s_waitcnt lgkmcnt(0)" ::: "memory");
    __builtin_amdgcn_s_barrier();
    __builtin_amdgcn_sched_barrier(0);
  }

  // ---- epilogue: tanh(acc + dec) . w2, reduced over n ----
  // C/D: D[row=quad*4+r][col] => m = mt*16+quad*4+r, n = wave*64+nt*16+col
  const float* decb = dec + b * D_SZ;
  float sums[4][4];
  #pragma unroll
  for (int mt = 0; mt < 4; mt++)
    #pragma unroll
    for (int r = 0; r < 4; r++) sums[mt][r] = 0.f;

  #pragma unroll
  for (int nt = 0; nt < 4; nt++) {
    int n = wave * 64 + nt * 16 + col;
    float dv = decb[n];
    float wv = w2[n];
    #pragma unroll
    for (int mt = 0; mt < 4; mt++)
      #pragma unroll
      for (int r = 0; r < 4; r++)
        sums[mt][r] += fast_tanh(acc[mt][nt][r] + dv) * wv;
  }
  #pragma unroll
  for (int mt = 0; mt < 4; mt++) {
    #pragma unroll
    for (int r = 0; r < 4; r++) {
      float v = sums[mt][r];
      v += __shfl_xor(v, 1, 16);
      v += __shfl_xor(v, 2, 16);
      v += __shfl_xor(v, 4, 16);
      v += __shfl_xor(v, 8, 16);
      if (col == 0) atomicAdd(&s_sc[mt * 16 + quad * 4 + r], v);  // 8 waves/row
    }
  }
  __syncthreads();
  if (t < 64) scores[b * L_SZ + l0 + t] = s_sc[t];
}

// ---------------------------------------------------------------------------
// Softmax: one WG (1024 threads) per batch row of 2048.
// ---------------------------------------------------------------------------
__global__ __launch_bounds__(1024) void softmax_k(const float* __restrict__ sc,
                                                  float* __restrict__ out) {
  int b = blockIdx.x, t = threadIdx.x;
  int wave = t >> 6, lane = t & 63;
  __shared__ float redm[16], reds[16];
  const float* row = sc + b * L_SZ;
  float v0 = row[t], v1 = row[t + 1024];
  float mx = fmaxf(v0, v1);
  #pragma unroll
  for (int off = 32; off >= 1; off >>= 1) mx = fmaxf(mx, __shfl_xor(mx, off, 64));
  if (lane == 0) redm[wave] = mx;
  __syncthreads();
  float m = redm[0];
  #pragma unroll
  for (int i = 1; i < 16; i++) m = fmaxf(m, redm[i]);
  v0 = __expf(v0 - m);
  v1 = __expf(v1 - m);
  float s = v0 + v1;
  #pragma unroll
  for (int off = 32; off >= 1; off >>= 1) s += __shfl_xor(s, off, 64);
  if (lane == 0) reds[wave] = s;
  __syncthreads();
  float sum = reds[0];
  #pragma unroll
  for (int i = 1; i < 16; i++) sum += reds[i];
  float inv = 1.0f / sum;
  out[b * L_SZ + t]        = v0 * inv;
  out[b * L_SZ + t + 1024] = v1 * inv;
}

extern "C" void kernel_launch(void* const* d_in, const int* in_sizes, int n_in,
                              void* d_out, int out_size, void* d_ws, size_t ws_size,
                              hipStream_t stream) {
  const float* d_hidden = (const float*)d_in[0];   // (32, 2, 512)
  const float* enc      = (const float*)d_in[1];   // (32, 2048, 512)
  const float* W1       = (const float*)d_in[2];   // (1536, 512)
  const float* b1       = (const float*)d_in[3];   // (512,)
  const float* w2       = (const float*)d_in[4];   // (512,)
  float* out = (float*)d_out;                      // (32, 2048)

  char* ws = (char*)d_ws;
  float*    dec = (float*)(ws + WS_DEC_OFF);
  ushort_t* Bt  = (ushort_t*)(ws + WS_BT_OFF);
  float*    sc  = (float*)(ws + WS_SC_OFF);

  prep_k<<<512, 256, 0, stream>>>(d_hidden, W1, b1, dec, Bt);
  main_k<<<dim3(32, 32), 512, 0, stream>>>(enc, Bt, dec, w2, sc);
  softmax_k<<<32, 1024, 0, stream>>>(sc, out);
}

// Round 7
// 249.299 us; speedup vs baseline: 1.0401x; 1.0401x over previous
//
#include <hip/hip_runtime.h>
#include <hip/hip_bf16.h>

// (B, LIN, E, D, N) = (32, 2048, 512, 512, 2)
#define L_SZ 2048
#define E_SZ 512
#define D_SZ 512
#define ND   1024
// ws layout: dec_proj (32*512 f32) | Bt (512*512 bf16, [n][k]) | scores (32*2048 f32)
#define WS_DEC_OFF 0
#define WS_BT_OFF  (32*512*4)
#define WS_SC_OFF  (32*512*4 + 512*512*2)

typedef unsigned short ushort_t;
typedef unsigned int   uint_t;
typedef __attribute__((ext_vector_type(8))) short short8;   // 8 bf16 (MFMA A/B frag)
typedef __attribute__((ext_vector_type(4))) float floatx4;  // MFMA C/D frag
typedef __attribute__((ext_vector_type(4))) float fvec4;    // clang-native float4

__device__ __forceinline__ ushort_t f2bf(float f) {
  uint_t u = __builtin_bit_cast(uint_t, f);
  u += 0x7fffu + ((u >> 16) & 1u);
  return (ushort_t)(u >> 16);
}

__device__ __forceinline__ float fast_tanh(float x) {
  float e = __expf(2.0f * x);
  return 1.0f - 2.0f * __builtin_amdgcn_rcpf(e + 1.0f);
}

// async 16B global->LDS DMA; lptr must be wave-uniform, HW deposits lane i at lptr + 16*i
__device__ __forceinline__ void dma16(const ushort_t* g, ushort_t* l) {
  __builtin_amdgcn_global_load_lds(
      (const __attribute__((address_space(1))) uint_t*)(const void*)g,
      (__attribute__((address_space(3))) uint_t*)(void*)l,
      16, 0, 0);
}

// ---------------------------------------------------------------------------
// Prep, 512 blocks:
//  blocks 0..255  : dec_proj[b][d] (b=blk>>3, d-tile=blk&7), k split 4-way + LDS reduce
//  blocks 256..511: Bt[n][k] = bf16(W1[1024+k][n]) via 32x32 LDS transpose tiles
// ---------------------------------------------------------------------------
__global__ __launch_bounds__(256) void prep_k(const float* __restrict__ dh,
                                              const float* __restrict__ W1,
                                              const float* __restrict__ b1,
                                              float* __restrict__ dec,
                                              ushort_t* __restrict__ Bt) {
  int blk = blockIdx.x, t = threadIdx.x;
  if (blk < 256) {
    int b = blk >> 3, d = (blk & 7) * 64 + (t & 63);
    int q = t >> 6;
    __shared__ float red[4][64];
    const float* dfb = dh + b * ND;
    float s = 0.f;
    #pragma unroll 8
    for (int k = q * 256; k < q * 256 + 256; k++)
      s = fmaf(dfb[k], W1[k * D_SZ + d], s);
    red[q][t & 63] = s;
    __syncthreads();
    if (q == 0)
      dec[b * D_SZ + d] = red[0][t] + red[1][t] + red[2][t] + red[3][t] + b1[d];
  } else {
    int tid = blk - 256;
    int tk = (tid >> 4) * 32, tn = (tid & 15) * 32;
    __shared__ float tile[32][33];
    int cc = t & 31, r8 = t >> 5;
    #pragma unroll
    for (int p = 0; p < 4; p++) {
      int r = r8 + p * 8;
      tile[r][cc] = W1[(ND + tk + r) * D_SZ + tn + cc];
    }
    __syncthreads();
    #pragma unroll
    for (int p = 0; p < 4; p++) {
      int nn = r8 + p * 8;
      Bt[(tn + nn) * E_SZ + tk + cc] = f2bf(tile[cc][nn]);
    }
  }
}

// ---------------------------------------------------------------------------
// Main (round 7): BM=128 traffic halving on the r6 schedule.
// Diagnosis r0-r6: time tracks BYTES THROUGH THE PER-CU VMEM PATH (~10-11
// B/cy/CU, = m13's HBM-copy per-CU rate) regardless of L2-hit (r1), schedule
// (r2/r6), occupancy (r5). Fix = fewer bytes: BM=128 -> 512 blocks -> Bt
// re-read 262 MB (was 512), total 393 MB (x0.60).
//
// WG = 512 threads (8 waves) = 128 rows x ALL 512 cols. K=512, BK=64, 8 windows.
// Wave w owns cols [w*64,w*64+64): 8mt x 4nt 16x16x32 tiles, acc[8][4]=128 VGPR.
// B: Bs double-buffered, wave w DEPOSITS exactly the rows it CONSUMES via 8
// dma16 (pre-XOR-swizzled source) -> no cross-wave B dependency; counted
// s_waitcnt vmcnt(12/12/8/0), never drained early. A: single 16KB buffer,
// loads issued 2 windows ahead, cvt+ds_write at window end between two
// lgkm-only barriers (no global drain at any barrier).
// LDS = 128(Bs) + 16(As) + 0.5 = 144.5 KB -> 1 block/CU.
// ---------------------------------------------------------------------------
__global__ __launch_bounds__(512, 2) void main_k(const float* __restrict__ enc,
                                                 const ushort_t* __restrict__ Bt,
                                                 const float* __restrict__ dec,
                                                 const float* __restrict__ w2,
                                                 float* __restrict__ scores) {
  const int b  = blockIdx.y;
  const int l0 = blockIdx.x * 128;
  const int t  = threadIdx.x;            // 0..511
  const int wave = t >> 6, lane = t & 63;
  const int col = lane & 15, quad = lane >> 4;

  __shared__ __align__(16) ushort_t Bs[2][512 * 64];  // 2 x 64 KB, [n][k] 128B rows, XOR-swz
  __shared__ __align__(16) ushort_t As[128 * 64];     // 16 KB,     [m][k] 128B rows, XOR-swz
  __shared__ float s_sc[128];

  if (t < 128) s_sc[t] = 0.f;

  floatx4 acc[8][4];
  #pragma unroll
  for (int mt = 0; mt < 8; mt++)
    #pragma unroll
    for (int nt = 0; nt < 4; nt++)
      acc[mt][nt] = (floatx4){0.f, 0.f, 0.f, 0.f};

  const float* arow = enc + (size_t)(b * L_SZ + l0) * E_SZ;

  // A: thread t owns rows am = t>>2 (0..127), chunks ac0 = (t&3)*2 and ac0+1
  // (each chunk = 8 floats -> 8 bf16 = 16B). 2 cvt-writes per window.
  const int am = t >> 2, ac0 = (t & 3) * 2;
  const float* aptr = arow + am * E_SZ + ac0 * 8;     // 16 consecutive floats
  const int awoff0 = am * 64 + ((ac0 ^ (am & 7)) << 3);
  const int awoff1 = am * 64 + (((ac0 + 1) ^ (am & 7)) << 3);

  // B DMA source mapping (r0/r6-verified): slot s = wave*512 + j*64 + lane;
  // n = s>>3 in [wave*64, wave*64+64); c = (s&7)^(n&7) (pre-swizzled source).
  const int bn0 = wave * 64 + (lane >> 3);
  const int bc0 = (lane & 7) ^ ((lane >> 3) & 7);
  const ushort_t* bptr0 = Bt + bn0 * E_SZ + bc0 * 8;

  // ---- prologue ----
  // issue order: A(0) 4 loads, B(0) 8 DMAs, A(1) 4 loads
  fvec4 a00 = *(const fvec4*)aptr;
  fvec4 a01 = *(const fvec4*)(aptr + 4);
  fvec4 a02 = *(const fvec4*)(aptr + 8);
  fvec4 a03 = *(const fvec4*)(aptr + 12);
  #pragma unroll
  for (int j = 0; j < 8; j++)
    dma16(bptr0 + j * 8 * E_SZ, &Bs[0][wave * 4096 + j * 512]);
  fvec4 ra0 = *(const fvec4*)(aptr + 64);
  fvec4 ra1 = *(const fvec4*)(aptr + 68);
  fvec4 ra2 = *(const fvec4*)(aptr + 72);
  fvec4 ra3 = *(const fvec4*)(aptr + 76);
  asm volatile("s_waitcnt vmcnt(12)" ::: "memory");   // drain A(0); keep B(0)+A(1)
  {
    union { short8 v; __hip_bfloat162 h[4]; } p0, p1;
    p0.h[0] = __float22bfloat162_rn(make_float2(a00.x, a00.y));
    p0.h[1] = __float22bfloat162_rn(make_float2(a00.z, a00.w));
    p0.h[2] = __float22bfloat162_rn(make_float2(a01.x, a01.y));
    p0.h[3] = __float22bfloat162_rn(make_float2(a01.z, a01.w));
    p1.h[0] = __float22bfloat162_rn(make_float2(a02.x, a02.y));
    p1.h[1] = __float22bfloat162_rn(make_float2(a02.z, a02.w));
    p1.h[2] = __float22bfloat162_rn(make_float2(a03.x, a03.y));
    p1.h[3] = __float22bfloat162_rn(make_float2(a03.z, a03.w));
    *(short8*)&As[awoff0] = p0.v;
    *(short8*)&As[awoff1] = p1.v;
  }
  asm volatile("s_waitcnt lgkmcnt(0)" ::: "memory");
  __builtin_amdgcn_s_barrier();
  __builtin_amdgcn_sched_barrier(0);

  fvec4 rn0, rn1, rn2, rn3;

  #pragma unroll 1
  for (int kw = 0; kw < 8; kw++) {
    const ushort_t* Bcur = &Bs[kw & 1][0];

    // ---- 1. issue A(kw+2) -> regs (4), B(kw+1) -> Bs[nxt] (8 DMAs) ----
    if (kw < 6) {
      const float* ap = aptr + (kw + 2) * 64;
      rn0 = *(const fvec4*)ap;
      rn1 = *(const fvec4*)(ap + 4);
      rn2 = *(const fvec4*)(ap + 8);
      rn3 = *(const fvec4*)(ap + 12);
    }
    if (kw < 7) {
      const ushort_t* bp = bptr0 + (kw + 1) * 64;
      ushort_t* bld = &Bs[(kw + 1) & 1][wave * 4096];
      #pragma unroll
      for (int j = 0; j < 8; j++)
        dma16(bp + j * 8 * E_SZ, bld + j * 512);
    }

    // ---- 2. counted wait: drain B(kw)+A(kw+1) (>=1 window old) ----
    if (kw < 6)       asm volatile("s_waitcnt vmcnt(12)" ::: "memory");
    else if (kw == 6) asm volatile("s_waitcnt vmcnt(8)"  ::: "memory");
    else              asm volatile("s_waitcnt vmcnt(0)"  ::: "memory");

    // ---- 3. MFMA on As (barrier-published) + Bs[cur] (self-deposited) ----
    #pragma unroll
    for (int ks = 0; ks < 2; ks++) {
      short8 af[8], bfr[4];
      #pragma unroll
      for (int mt = 0; mt < 8; mt++) {
        int m = mt * 16 + col;
        af[mt] = *(const short8*)&As[m * 64 + ((((ks << 2) + quad) ^ (m & 7)) << 3)];
      }
      #pragma unroll
      for (int nt = 0; nt < 4; nt++) {
        int n = wave * 64 + nt * 16 + col;
        bfr[nt] = *(const short8*)&Bcur[n * 64 + ((((ks << 2) + quad) ^ (n & 7)) << 3)];
      }
      #pragma unroll
      for (int mt = 0; mt < 8; mt++)
        #pragma unroll
        for (int nt = 0; nt < 4; nt++)
          acc[mt][nt] = __builtin_amdgcn_mfma_f32_16x16x32_bf16(af[mt], bfr[nt], acc[mt][nt], 0, 0, 0);
    }

    // ---- 4. barrier #1: all waves done READING As(kw) ----
    asm volatile("s_waitcnt lgkmcnt(0)" ::: "memory");
    __builtin_amdgcn_s_barrier();

    // ---- 5. cvt A(kw+1) regs -> As; barrier #2 publishes it ----
    if (kw < 7) {
      union { short8 v; __hip_bfloat162 h[4]; } p0, p1;
      p0.h[0] = __float22bfloat162_rn(make_float2(ra0.x, ra0.y));
      p0.h[1] = __float22bfloat162_rn(make_float2(ra0.z, ra0.w));
      p0.h[2] = __float22bfloat162_rn(make_float2(ra1.x, ra1.y));
      p0.h[3] = __float22bfloat162_rn(make_float2(ra1.z, ra1.w));
      p1.h[0] = __float22bfloat162_rn(make_float2(ra2.x, ra2.y));
      p1.h[1] = __float22bfloat162_rn(make_float2(ra2.z, ra2.w));
      p1.h[2] = __float22bfloat162_rn(make_float2(ra3.x, ra3.y));
      p1.h[3] = __float22bfloat162_rn(make_float2(ra3.z, ra3.w));
      *(short8*)&As[awoff0] = p0.v;
      *(short8*)&As[awoff1] = p1.v;
      ra0 = rn0; ra1 = rn1; ra2 = rn2; ra3 = rn3;
    }
    asm volatile("s_waitcnt lgkmcnt(0)" ::: "memory");
    __builtin_amdgcn_s_barrier();
    __builtin_amdgcn_sched_barrier(0);
  }

  // ---- epilogue: tanh(acc + dec) . w2, reduced over n ----
  // C/D: D[row=quad*4+r][col] => m = mt*16+quad*4+r, n = wave*64+nt*16+col
  const float* decb = dec + b * D_SZ;
  float sums[8][4];
  #pragma unroll
  for (int mt = 0; mt < 8; mt++)
    #pragma unroll
    for (int r = 0; r < 4; r++) sums[mt][r] = 0.f;

  #pragma unroll
  for (int nt = 0; nt < 4; nt++) {
    int n = wave * 64 + nt * 16 + col;
    float dv = decb[n];
    float wv = w2[n];
    #pragma unroll
    for (int mt = 0; mt < 8; mt++)
      #pragma unroll
      for (int r = 0; r < 4; r++)
        sums[mt][r] += fast_tanh(acc[mt][nt][r] + dv) * wv;
  }
  #pragma unroll
  for (int mt = 0; mt < 8; mt++) {
    #pragma unroll
    for (int r = 0; r < 4; r++) {
      float v = sums[mt][r];
      v += __shfl_xor(v, 1, 16);
      v += __shfl_xor(v, 2, 16);
      v += __shfl_xor(v, 4, 16);
      v += __shfl_xor(v, 8, 16);
      if (col == 0) atomicAdd(&s_sc[mt * 16 + quad * 4 + r], v);  // 8 waves/row
    }
  }
  __syncthreads();
  if (t < 128) scores[b * L_SZ + l0 + t] = s_sc[t];
}

// ---------------------------------------------------------------------------
// Softmax: one WG (1024 threads) per batch row of 2048.
// ---------------------------------------------------------------------------
__global__ __launch_bounds__(1024) void softmax_k(const float* __restrict__ sc,
                                                  float* __restrict__ out) {
  int b = blockIdx.x, t = threadIdx.x;
  int wave = t >> 6, lane = t & 63;
  __shared__ float redm[16], reds[16];
  const float* row = sc + b * L_SZ;
  float v0 = row[t], v1 = row[t + 1024];
  float mx = fmaxf(v0, v1);
  #pragma unroll
  for (int off = 32; off >= 1; off >>= 1) mx = fmaxf(mx, __shfl_xor(mx, off, 64));
  if (lane == 0) redm[wave] = mx;
  __syncthreads();
  float m = redm[0];
  #pragma unroll
  for (int i = 1; i < 16; i++) m = fmaxf(m, redm[i]);
  v0 = __expf(v0 - m);
  v1 = __expf(v1 - m);
  float s = v0 + v1;
  #pragma unroll
  for (int off = 32; off >= 1; off >>= 1) s += __shfl_xor(s, off, 64);
  if (lane == 0) reds[wave] = s;
  __syncthreads();
  float sum = reds[0];
  #pragma unroll
  for (int i = 1; i < 16; i++) sum += reds[i];
  float inv = 1.0f / sum;
  out[b * L_SZ + t]        = v0 * inv;
  out[b * L_SZ + t + 1024] = v1 * inv;
}

extern "C" void kernel_launch(void* const* d_in, const int* in_sizes, int n_in,
                              void* d_out, int out_size, void* d_ws, size_t ws_size,
                              hipStream_t stream) {
  const float* d_hidden = (const float*)d_in[0];   // (32, 2, 512)
  const float* enc      = (const float*)d_in[1];   // (32, 2048, 512)
  const float* W1       = (const float*)d_in[2];   // (1536, 512)
  const float* b1       = (const float*)d_in[3];   // (512,)
  const float* w2       = (const float*)d_in[4];   // (512,)
  float* out = (float*)d_out;                      // (32, 2048)

  char* ws = (char*)d_ws;
  float*    dec = (float*)(ws + WS_DEC_OFF);
  ushort_t* Bt  = (ushort_t*)(ws + WS_BT_OFF);
  float*    sc  = (float*)(ws + WS_SC_OFF);

  prep_k<<<512, 256, 0, stream>>>(d_hidden, W1, b1, dec, Bt);
  main_k<<<dim3(16, 32), 512, 0, stream>>>(enc, Bt, dec, w2, sc);
  softmax_k<<<32, 1024, 0, stream>>>(sc, out);
}